// Round 1
// baseline (691.097 us; speedup 1.0000x reference)
//
#include <hip/hip_runtime.h>
#include <hip/hip_bf16.h>
#include <stdint.h>

typedef __attribute__((ext_vector_type(8))) short short8;   // 8 bf16 (4 VGPRs)
typedef __attribute__((ext_vector_type(4))) float f32x4;    // 4 fp32 acc
typedef __hip_bfloat16 bf16;

// Problem constants
#define NB   8
#define LSEQ 2048
#define NM   256
#define DMODEL 1024
#define DO   256
#define BLR  16384   /* NB*LSEQ rows */
#define NCH  32      /* scan chunks */
#define CLK  64      /* chunk length */

__device__ __forceinline__ float sigm(float x) { return 1.f / (1.f + __expf(-x)); }

__device__ __forceinline__ void gl_lds16(const void* g, void* l) {
  __builtin_amdgcn_global_load_lds((const __attribute__((address_space(1))) void*)g,
                                   (__attribute__((address_space(3))) void*)l, 16, 0, 0);
}

// ---------------- small kernels ----------------

__global__ __launch_bounds__(256) void cvt_bf16_kernel(const float* __restrict__ in,
                                                       bf16* __restrict__ out, int n) {
  int i = blockIdx.x * 256 + threadIdx.x;
  if (i < n) out[i] = __float2bfloat16(in[i]);
}

__global__ __launch_bounds__(256) void e8l2a_kernel(const float* __restrict__ log_a,
                                                    float* __restrict__ e8, int n) {
  int i = blockIdx.x * 256 + threadIdx.x;
  if (i < n) {
    float ab = 1.f / (1.f + expf(-log_a[i]));   // a_base = sigmoid(log_a)
    e8[i] = 8.f * log2f(ab);                    // a_t = exp2(r * 8*log2(a_base))
  }
}

__global__ __launch_bounds__(256) void ema_kernel(const float* __restrict__ cpt,
                                                  const float* __restrict__ bprobs,
                                                  const int* __restrict__ bidx,
                                                  float* __restrict__ smoothed) {
  int b = blockIdx.x >> 2;
  int c = ((blockIdx.x & 3) << 8) + threadIdx.x;
  __shared__ float p[NM];
  p[threadIdx.x] = bprobs[b * LSEQ + bidx[b * NM + threadIdx.x]];
  __syncthreads();
  const float* cp = cpt + (size_t)b * NM * DMODEL + c;
  float* sp = smoothed + (size_t)b * NM * DMODEL + c;
  float h = 0.f;
  for (int m = 0; m < NM; ++m) {
    float pm = p[m];
    h = pm * cp[(size_t)m * DMODEL] + (1.f - pm) * h;
    sp[(size_t)m * DMODEL] = h;
  }
}

__global__ __launch_bounds__(256) void bucket_kernel(const int* __restrict__ bidx,
                                                     int* __restrict__ bucket) {
  int i = blockIdx.x * 256 + threadIdx.x;  // 0..BLR-1
  int b = i >> 11, l = i & 2047;
  const int* bi = bidx + b * NM;
  int lo = 0, hi = NM;                     // count of bi[m] <= l  (side='right')
  while (lo < hi) {
    int mid = (lo + hi) >> 1;
    if (bi[mid] <= l) lo = mid + 1; else hi = mid;
  }
  int v = lo - 1;
  bucket[i] = v < 0 ? 0 : v;
}

__global__ __launch_bounds__(256) void conv_kernel(const float* __restrict__ x,
                                                   const float* __restrict__ cw,
                                                   const float* __restrict__ cb,
                                                   float* __restrict__ xc,
                                                   bf16* __restrict__ xcb) {
  int i = blockIdx.x * 256 + threadIdx.x;  // over BLR*DO
  int c = i & 255;
  int bl = i >> 8;
  int l = bl & 2047;
  float4 w4 = ((const float4*)cw)[c];      // w[c][0..3]
  const float* wf = (const float*)&w4;
  float s = cb[c];
#pragma unroll
  for (int kk = 0; kk < 4; ++kk) {
    int ll = l - 3 + kk;                   // causal pad (3,0)
    if (ll >= 0) s += wf[kk] * x[i + (kk - 3) * 256];
  }
  xc[i] = s;
  xcb[i] = __float2bfloat16(s);
}

// 3-phase chunked linear-recurrence scan: h_t = a_t*h + s_t
__global__ __launch_bounds__(256) void scan1_kernel(const float* __restrict__ a,
                                                    const float* __restrict__ s,
                                                    float* __restrict__ Ac,
                                                    float* __restrict__ Sc) {
  int b = blockIdx.x >> 5, ch = blockIdx.x & 31, c = threadIdx.x;
  size_t bse = ((size_t)b * LSEQ + ch * CLK) * 256 + c;
  float A = 1.f, S = 0.f;
  for (int t = 0; t < CLK; ++t) {
    float at = a[bse + (size_t)t * 256];
    float st = s[bse + (size_t)t * 256];
    A *= at;
    S = at * S + st;
  }
  int o = blockIdx.x * 256 + c;
  Ac[o] = A; Sc[o] = S;
}

__global__ __launch_bounds__(256) void scan2_kernel(const float* __restrict__ Ac,
                                                    const float* __restrict__ Sc,
                                                    float* __restrict__ Hin) {
  int b = blockIdx.x, c = threadIdx.x;
  float h = 0.f;
  for (int ch = 0; ch < NCH; ++ch) {
    int idx = (b * NCH + ch) * 256 + c;
    Hin[idx] = h;               // exclusive prefix: incoming state of chunk
    h = Ac[idx] * h + Sc[idx];
  }
}

__global__ __launch_bounds__(256) void scan3_kernel(const float* __restrict__ a,
                                                    const float* __restrict__ s,
                                                    const float* __restrict__ Hin,
                                                    bf16* __restrict__ hs) {
  int b = blockIdx.x >> 5, ch = blockIdx.x & 31, c = threadIdx.x;
  float h = Hin[blockIdx.x * 256 + c];
  size_t bse = ((size_t)b * LSEQ + ch * CLK) * 256 + c;
  for (int t = 0; t < CLK; ++t) {
    float at = a[bse + (size_t)t * 256];
    float st = s[bse + (size_t)t * 256];
    h = at * h + st;
    hs[bse + (size_t)t * 256] = __float2bfloat16(h);
  }
}

__global__ __launch_bounds__(256) void rmsnorm256_kernel(const float* __restrict__ in,
                                                         const float* __restrict__ w,
                                                         float* __restrict__ outf,
                                                         bf16* __restrict__ outb) {
  int row = blockIdx.x, c = threadIdx.x;
  size_t idx = (size_t)row * 256 + c;
  float v = in[idx];
  float ss = v * v;
#pragma unroll
  for (int ofs = 32; ofs > 0; ofs >>= 1) ss += __shfl_down(ss, ofs, 64);
  __shared__ float wsum[4];
  if ((c & 63) == 0) wsum[c >> 6] = ss;
  __syncthreads();
  float tot = wsum[0] + wsum[1] + wsum[2] + wsum[3];
  float sc = rsqrtf(tot * (1.f / 256.f) + 1e-6f);
  float o = v * sc * w[c];
  outf[idx] = o;
  outb[idx] = __float2bfloat16(o);
}

__global__ __launch_bounds__(256) void rmsnorm1024_kernel(const float* __restrict__ in,
                                                          const float* __restrict__ w,
                                                          float* __restrict__ out) {
  int row = blockIdx.x, t = threadIdx.x;
  const float4* ip = (const float4*)(in + (size_t)row * 1024);
  float4 v = ip[t];
  float ss = v.x * v.x + v.y * v.y + v.z * v.z + v.w * v.w;
#pragma unroll
  for (int ofs = 32; ofs > 0; ofs >>= 1) ss += __shfl_down(ss, ofs, 64);
  __shared__ float wsum[4];
  if ((t & 63) == 0) wsum[t >> 6] = ss;
  __syncthreads();
  float tot = wsum[0] + wsum[1] + wsum[2] + wsum[3];
  float sc = rsqrtf(tot * (1.f / 1024.f) + 1e-6f);
  float4 wv = ((const float4*)w)[t];
  float4 o;
  o.x = v.x * sc * wv.x; o.y = v.y * sc * wv.y;
  o.z = v.z * sc * wv.z; o.w = v.w * sc * wv.w;
  ((float4*)(out + (size_t)row * 1024))[t] = o;
}

// ---------------- MFMA GEMM: C[M,N] = A[M,K] * W[N,K]^T, fused epilogues ----------------
// Tile 128x128, BK=64, 256 threads = 4 waves (2x2), each wave 64x64 = 4x4 mfma 16x16x32 tiles.
// LDS XOR-swizzle on k8-groups so ds_read_b128 is <=2-way bank-aliased (free, m136);
// staging via global_load_lds width=16 (wave-uniform base + lane*16 naturally satisfied).

struct EpA {
  float* outf;
  bf16* outb;
  const float* bias;
  const float* e8l2a;
  const float* enc;
  const float* p;
  const int* bucket;
  const float* smoothed;
  const float* xconv;
  const float* abuf;
};

template <int EP>
__global__ __launch_bounds__(256) void gemm_bt(const bf16* __restrict__ A,
                                               const bf16* __restrict__ W,
                                               int N, int K, EpA ep) {
  __shared__ __align__(16) bf16 As[128 * 64];
  __shared__ __align__(16) bf16 Bs[128 * 64];
  const int t = threadIdx.x;
  const int lane = t & 63;
  const int wv = t >> 6;
  const int wm = wv >> 1, wn = wv & 1;
  const int quad = lane >> 4, l16 = lane & 15;
  const int bm = blockIdx.y << 7, bn = blockIdx.x << 7;

  f32x4 acc[4][4] = {};

  for (int k0 = 0; k0 < K; k0 += 64) {
    __syncthreads();
#pragma unroll
    for (int i = 0; i < 4; ++i) {
      int slot = i * 256 + t;
      int m = slot >> 3;
      int lk8 = (slot & 7) ^ (m & 7);  // logical k8 stored at physical slot
      gl_lds16(A + (size_t)(bm + m) * K + k0 + lk8 * 8, As + slot * 8);
      gl_lds16(W + (size_t)(bn + m) * K + k0 + lk8 * 8, Bs + slot * 8);
    }
    __syncthreads();
#pragma unroll
    for (int ks = 0; ks < 2; ++ks) {
      short8 af[4], bfr[4];
#pragma unroll
      for (int i = 0; i < 4; ++i) {
        int m = wm * 64 + i * 16 + l16;
        int pa = (ks * 4 + quad) ^ (m & 7);
        af[i] = *(const short8*)(As + m * 64 + pa * 8);
        int n = wn * 64 + i * 16 + l16;
        int pb = (ks * 4 + quad) ^ (n & 7);
        bfr[i] = *(const short8*)(Bs + n * 64 + pb * 8);
      }
#pragma unroll
      for (int i = 0; i < 4; ++i)
#pragma unroll
        for (int j = 0; j < 4; ++j)
          acc[i][j] = __builtin_amdgcn_mfma_f32_16x16x32_bf16(af[i], bfr[j], acc[i][j], 0, 0, 0);
    }
  }

  // epilogue: C row=(lane>>4)*4+r, col=lane&15 (verified m89/m91)
#pragma unroll
  for (int i = 0; i < 4; ++i) {
#pragma unroll
    for (int j = 0; j < 4; ++j) {
#pragma unroll
      for (int r = 0; r < 4; ++r) {
        int m = bm + wm * 64 + i * 16 + quad * 4 + r;
        int n = bn + wn * 64 + j * 16 + l16;
        size_t idx = (size_t)m * N + n;
        float v = acc[i][j][r];
        if (EP == 0) {
          ep.outf[idx] = v;
        } else if (EP == 1) {  // gate + plugback (N == DMODEL here)
          float g = sigm(v + ep.bias[n]);
          float pm = ep.p[m];
          int bb = m >> 11;
          float sm = ep.smoothed[((size_t)(bb * NM + ep.bucket[m])) * DMODEL + n];
          ep.outb[idx] = __float2bfloat16((1.f - pm) * g * ep.enc[idx] + sm);
        } else if (EP == 3) {  // r_t -> a_t
          float rr = sigm(v + ep.bias[n]);
          ep.outf[idx] = exp2f(rr * ep.e8l2a[n]);
        } else {               // EP == 4: i_t -> s_t = sqrt(1-a^2)*i*xconv
          float ii = sigm(v + ep.bias[n]);
          float u = ii * ep.xconv[idx];
          float a = ep.abuf[idx];
          ep.outf[idx] = sqrtf(fmaxf(1.f - a * a, 0.f)) * u;
        }
      }
    }
  }
}

// ---------------- launch ----------------

extern "C" void kernel_launch(void* const* d_in, const int* in_sizes, int n_in,
                              void* d_out, int out_size, void* d_ws, size_t ws_size,
                              hipStream_t stream) {
  const float* concept_out = (const float*)d_in[0];
  const float* encoder_out = (const float*)d_in[1];
  const float* bprobs      = (const float*)d_in[2];
  const int*   bidx        = (const int*)d_in[3];
  const float* gate_w      = (const float*)d_in[4];
  const float* gate_b      = (const float*)d_in[5];
  const float* down_w      = (const float*)d_in[6];
  const float* up_w        = (const float*)d_in[7];
  const float* norm_out_w  = (const float*)d_in[8];
  const float* rc_w        = (const float*)d_in[9];
  const float* rc_b        = (const float*)d_in[10];
  const float* wr_w        = (const float*)d_in[11];
  const float* wr_b        = (const float*)d_in[12];
  const float* wi_w        = (const float*)d_in[13];
  const float* wi_b        = (const float*)d_in[14];
  const float* log_a       = (const float*)d_in[15];
  const float* ow_w        = (const float*)d_in[16];
  const float* rn_w        = (const float*)d_in[17];
  float* out = (float*)d_out;
  (void)in_sizes; (void)n_in; (void)out_size; (void)ws_size;

  // workspace arena (~119 MB peak with aliasing)
  char* base = (char*)d_ws;
  size_t off = 0;
  auto alloc = [&](size_t bytes) -> char* {
    char* p = base + off;
    off += (bytes + 255) & ~(size_t)255;
    return p;
  };
  float* smoothed = (float*)alloc((size_t)NB * NM * DMODEL * 4);   // 8 MB
  int*   bucket   = (int*)alloc((size_t)BLR * 4);
  bf16*  gate_wb  = (bf16*)alloc((size_t)DMODEL * DMODEL * 2);
  bf16*  down_wb  = (bf16*)alloc((size_t)DO * DMODEL * 2);
  bf16*  up_wb    = (bf16*)alloc((size_t)DMODEL * DO * 2);
  bf16*  wrb      = (bf16*)alloc((size_t)3 * DO * DO * 2);
  bf16*  wib      = (bf16*)alloc((size_t)3 * DO * DO * 2);
  bf16*  owb      = (bf16*)alloc((size_t)3 * DO * DO * 2);
  float* e8       = (float*)alloc(3 * DO * 4);
  float* Ac       = (float*)alloc((size_t)NB * NCH * DO * 4);
  float* Sc       = (float*)alloc((size_t)NB * NCH * DO * 4);
  float* Hin      = (float*)alloc((size_t)NB * NCH * DO * 4);
  float* xbuf     = (float*)alloc((size_t)BLR * DO * 4);           // 16 MB
  bf16*  xb       = (bf16*)alloc((size_t)BLR * DO * 2);            // 8 MB
  char*  RA       = alloc(80ull << 20);                            // reused region
  // phase 1 overlays
  bf16*  encb = (bf16*)RA;                          // 32 MB (dead after G1)
  bf16*  h0b  = (bf16*)(RA + (32ull << 20));        // 32 MB (dead after G2)
  // layer overlays
  float* xconv  = (float*)RA;                       // 16 MB
  bf16*  xconvb = (bf16*)(RA + (16ull << 20));      //  8 MB
  float* abuf   = (float*)(RA + (24ull << 20));     // 16 MB
  float* sbuf   = (float*)(RA + (40ull << 20));     // 16 MB
  bf16*  hsb    = (bf16*)(RA + (56ull << 20));      //  8 MB
  float* tmp    = (float*)(RA + (64ull << 20));     // 16 MB
  // final overlay
  float* tmp2   = (float*)RA;                       // 64 MB

  auto cvt = [&](const float* src, bf16* dst, int n) {
    cvt_bf16_kernel<<<(n + 255) / 256, 256, 0, stream>>>(src, dst, n);
  };
  cvt(encoder_out, encb, BLR * DMODEL);
  cvt(gate_w, gate_wb, DMODEL * DMODEL);
  cvt(down_w, down_wb, DO * DMODEL);
  cvt(up_w, up_wb, DMODEL * DO);
  cvt(wr_w, wrb, 3 * DO * DO);
  cvt(wi_w, wib, 3 * DO * DO);
  cvt(ow_w, owb, 3 * DO * DO);
  e8l2a_kernel<<<3, 256, 0, stream>>>(log_a, e8, 3 * DO);
  ema_kernel<<<NB * 4, 256, 0, stream>>>(concept_out, bprobs, bidx, smoothed);
  bucket_kernel<<<BLR / 256, 256, 0, stream>>>(bidx, bucket);

  EpA ep;
  // G1: gate GEMM + fused gated residual + plugback -> h0 (bf16)
  ep = EpA{};
  ep.outb = h0b; ep.bias = gate_b; ep.enc = encoder_out; ep.p = bprobs;
  ep.bucket = bucket; ep.smoothed = smoothed;
  gemm_bt<1><<<dim3(DMODEL / 128, BLR / 128), 256, 0, stream>>>(encb, gate_wb, DMODEL, DMODEL, ep);
  // G2: down projection -> x (f32)
  ep = EpA{}; ep.outf = xbuf;
  gemm_bt<0><<<dim3(DO / 128, BLR / 128), 256, 0, stream>>>(h0b, down_wb, DO, DMODEL, ep);

  for (int k = 0; k < 3; ++k) {
    conv_kernel<<<BLR, 256, 0, stream>>>(xbuf, rc_w + k * DO * 4, rc_b + k * DO, xconv, xconvb);
    ep = EpA{}; ep.outf = abuf; ep.bias = wr_b + k * DO; ep.e8l2a = e8 + k * DO;
    gemm_bt<3><<<dim3(DO / 128, BLR / 128), 256, 0, stream>>>(xconvb, wrb + k * DO * DO, DO, DO, ep);
    ep = EpA{}; ep.outf = sbuf; ep.bias = wi_b + k * DO; ep.xconv = xconv; ep.abuf = abuf;
    gemm_bt<4><<<dim3(DO / 128, BLR / 128), 256, 0, stream>>>(xconvb, wib + k * DO * DO, DO, DO, ep);
    scan1_kernel<<<NB * NCH, 256, 0, stream>>>(abuf, sbuf, Ac, Sc);
    scan2_kernel<<<NB, 256, 0, stream>>>(Ac, Sc, Hin);
    scan3_kernel<<<NB * NCH, 256, 0, stream>>>(abuf, sbuf, Hin, hsb);
    ep = EpA{}; ep.outf = tmp;
    gemm_bt<0><<<dim3(DO / 128, BLR / 128), 256, 0, stream>>>(hsb, owb + k * DO * DO, DO, DO, ep);
    rmsnorm256_kernel<<<BLR, 256, 0, stream>>>(tmp, rn_w + k * DO, xbuf, xb);
  }

  // G6: up projection -> tmp2 (f32), then final rmsnorm -> out
  ep = EpA{}; ep.outf = tmp2;
  gemm_bt<0><<<dim3(DMODEL / 128, BLR / 128), 256, 0, stream>>>(xb, up_wb, DMODEL, DO, ep);
  rmsnorm1024_kernel<<<BLR, 256, 0, stream>>>(tmp2, norm_out_w, out);
}

// Round 2
// 664.339 us; speedup vs baseline: 1.0403x; 1.0403x over previous
//
#include <hip/hip_runtime.h>
#include <hip/hip_bf16.h>
#include <stdint.h>

typedef __attribute__((ext_vector_type(8))) short short8;   // 8 bf16 (4 VGPRs)
typedef __attribute__((ext_vector_type(4))) float f32x4;    // 4 fp32 acc
typedef __hip_bfloat16 bf16;

// Problem constants
#define NB   8
#define LSEQ 2048
#define NM   256
#define DMODEL 1024
#define DO   256
#define BLR  16384   /* NB*LSEQ rows */
#define NCH  32      /* scan chunks */
#define CLK  64      /* chunk length */

__device__ __forceinline__ float sigm(float x) { return 1.f / (1.f + __expf(-x)); }

__device__ __forceinline__ void gl_lds16(const void* g, void* l) {
  __builtin_amdgcn_global_load_lds((const __attribute__((address_space(1))) void*)g,
                                   (__attribute__((address_space(3))) void*)l, 16, 0, 0);
}

// ---------------- small kernels ----------------

__global__ __launch_bounds__(256) void cvt_bf16_kernel(const float* __restrict__ in,
                                                       bf16* __restrict__ out, int n) {
  int i = blockIdx.x * 256 + threadIdx.x;
  if (i < n) out[i] = __float2bfloat16(in[i]);
}

__global__ __launch_bounds__(256) void e8l2a_kernel(const float* __restrict__ log_a,
                                                    float* __restrict__ e8, int n) {
  int i = blockIdx.x * 256 + threadIdx.x;
  if (i < n) {
    float ab = 1.f / (1.f + expf(-log_a[i]));   // a_base = sigmoid(log_a)
    e8[i] = 8.f * log2f(ab);                    // a_t = exp2(r * 8*log2(a_base))
  }
}

__global__ __launch_bounds__(256) void ema_kernel(const float* __restrict__ cpt,
                                                  const float* __restrict__ bprobs,
                                                  const int* __restrict__ bidx,
                                                  float* __restrict__ smoothed) {
  int b = blockIdx.x >> 2;
  int c = ((blockIdx.x & 3) << 8) + threadIdx.x;
  __shared__ float p[NM];
  p[threadIdx.x] = bprobs[b * LSEQ + bidx[b * NM + threadIdx.x]];
  __syncthreads();
  const float* cp = cpt + (size_t)b * NM * DMODEL + c;
  float* sp = smoothed + (size_t)b * NM * DMODEL + c;
  float h = 0.f;
  for (int m = 0; m < NM; ++m) {
    float pm = p[m];
    h = pm * cp[(size_t)m * DMODEL] + (1.f - pm) * h;
    sp[(size_t)m * DMODEL] = h;
  }
}

__global__ __launch_bounds__(256) void bucket_kernel(const int* __restrict__ bidx,
                                                     int* __restrict__ bucket) {
  int i = blockIdx.x * 256 + threadIdx.x;  // 0..BLR-1
  int b = i >> 11, l = i & 2047;
  const int* bi = bidx + b * NM;
  int lo = 0, hi = NM;                     // count of bi[m] <= l  (side='right')
  while (lo < hi) {
    int mid = (lo + hi) >> 1;
    if (bi[mid] <= l) lo = mid + 1; else hi = mid;
  }
  int v = lo - 1;
  bucket[i] = v < 0 ? 0 : v;
}

// depthwise causal conv k=4, bf16 in/out
__global__ __launch_bounds__(256) void conv_kernel(const bf16* __restrict__ x,
                                                   const float* __restrict__ cw,
                                                   const float* __restrict__ cb,
                                                   bf16* __restrict__ xcb) {
  int i = blockIdx.x * 256 + threadIdx.x;  // over BLR*DO
  int c = i & 255;
  int bl = i >> 8;
  int l = bl & 2047;
  float4 w4 = ((const float4*)cw)[c];      // w[c][0..3]
  const float* wf = (const float*)&w4;
  float s = cb[c];
#pragma unroll
  for (int kk = 0; kk < 4; ++kk) {
    int ll = l - 3 + kk;                   // causal pad (3,0)
    if (ll >= 0) s += wf[kk] * __bfloat162float(x[i + (kk - 3) * 256]);
  }
  xcb[i] = __float2bfloat16(s);
}

// 3-phase chunked linear-recurrence scan: h_t = a_t*h + s_t  (a f32, s bf16)
__global__ __launch_bounds__(256) void scan1_kernel(const float* __restrict__ a,
                                                    const bf16* __restrict__ s,
                                                    float* __restrict__ Ac,
                                                    float* __restrict__ Sc) {
  int b = blockIdx.x >> 5, ch = blockIdx.x & 31, c = threadIdx.x;
  size_t bse = ((size_t)b * LSEQ + ch * CLK) * 256 + c;
  float A = 1.f, S = 0.f;
  for (int t = 0; t < CLK; ++t) {
    float at = a[bse + (size_t)t * 256];
    float st = __bfloat162float(s[bse + (size_t)t * 256]);
    A *= at;
    S = at * S + st;
  }
  int o = blockIdx.x * 256 + c;
  Ac[o] = A; Sc[o] = S;
}

__global__ __launch_bounds__(256) void scan2_kernel(const float* __restrict__ Ac,
                                                    const float* __restrict__ Sc,
                                                    float* __restrict__ Hin) {
  int b = blockIdx.x, c = threadIdx.x;
  float h = 0.f;
  for (int ch = 0; ch < NCH; ++ch) {
    int idx = (b * NCH + ch) * 256 + c;
    Hin[idx] = h;               // exclusive prefix: incoming state of chunk
    h = Ac[idx] * h + Sc[idx];
  }
}

__global__ __launch_bounds__(256) void scan3_kernel(const float* __restrict__ a,
                                                    const bf16* __restrict__ s,
                                                    const float* __restrict__ Hin,
                                                    bf16* __restrict__ hs) {
  int b = blockIdx.x >> 5, ch = blockIdx.x & 31, c = threadIdx.x;
  float h = Hin[blockIdx.x * 256 + c];
  size_t bse = ((size_t)b * LSEQ + ch * CLK) * 256 + c;
  for (int t = 0; t < CLK; ++t) {
    float at = a[bse + (size_t)t * 256];
    float st = __bfloat162float(s[bse + (size_t)t * 256]);
    h = at * h + st;
    hs[bse + (size_t)t * 256] = __float2bfloat16(h);
  }
}

// rmsnorm over 256 channels, bf16 in -> bf16 out
__global__ __launch_bounds__(256) void rmsnorm256_kernel(const bf16* __restrict__ in,
                                                         const float* __restrict__ w,
                                                         bf16* __restrict__ outb) {
  int row = blockIdx.x, c = threadIdx.x;
  size_t idx = (size_t)row * 256 + c;
  float v = __bfloat162float(in[idx]);
  float ss = v * v;
#pragma unroll
  for (int ofs = 32; ofs > 0; ofs >>= 1) ss += __shfl_down(ss, ofs, 64);
  __shared__ float wsum[4];
  if ((c & 63) == 0) wsum[c >> 6] = ss;
  __syncthreads();
  float tot = wsum[0] + wsum[1] + wsum[2] + wsum[3];
  float sc = rsqrtf(tot * (1.f / 256.f) + 1e-6f);
  outb[idx] = __float2bfloat16(v * sc * w[c]);
}

// final rmsnorm over 1024, bf16 in -> f32 out
__global__ __launch_bounds__(256) void rmsnorm1024_kernel(const bf16* __restrict__ in,
                                                          const float* __restrict__ w,
                                                          float* __restrict__ out) {
  int row = blockIdx.x, t = threadIdx.x;
  const short8* ip = (const short8*)(in + (size_t)row * 1024);
  // each thread: 4 bf16 (8B)
  ushort4 raw = ((const ushort4*)ip)[t];
  float v0 = __bfloat162float(*(const bf16*)&raw.x);
  float v1 = __bfloat162float(*(const bf16*)&raw.y);
  float v2 = __bfloat162float(*(const bf16*)&raw.z);
  float v3 = __bfloat162float(*(const bf16*)&raw.w);
  float ss = v0 * v0 + v1 * v1 + v2 * v2 + v3 * v3;
#pragma unroll
  for (int ofs = 32; ofs > 0; ofs >>= 1) ss += __shfl_down(ss, ofs, 64);
  __shared__ float wsum[4];
  if ((t & 63) == 0) wsum[t >> 6] = ss;
  __syncthreads();
  float tot = wsum[0] + wsum[1] + wsum[2] + wsum[3];
  float sc = rsqrtf(tot * (1.f / 1024.f) + 1e-6f);
  float4 wv = ((const float4*)w)[t];
  float4 o;
  o.x = v0 * sc * wv.x; o.y = v1 * sc * wv.y;
  o.z = v2 * sc * wv.z; o.w = v3 * sc * wv.w;
  ((float4*)(out + (size_t)row * 1024))[t] = o;
}

// ---------------- MFMA GEMM: C[M,N] = A[M,K] * W[N,K]^T, fused epilogues ----------------
// Tile 128x128, BK=64, 256 threads = 4 waves (2x2), each wave 64x64 = 4x4 mfma 16x16x32 tiles.
// Grid: x = bm (128 row-tiles), y = bn. Blocks sharing an A-tile differ in linear ID by
// multiples of gridDim.x=128 == 0 mod 8 -> land on the SAME XCD -> A fetched once per L2.
// LDS XOR-swizzle on k8-groups so ds_read_b128 is <=2-way bank-aliased (free, m136);
// staging via global_load_lds width=16.

struct EpA {
  float* outf;
  bf16* outb;
  const float* bias;
  const float* e8l2a;
  const bf16* encb;
  const float* p;
  const int* bucket;
  const float* smoothed;
  const bf16* xconvb;
  const float* abuf;
};

template <int EP>
__global__ __launch_bounds__(256) void gemm_bt(const bf16* __restrict__ A,
                                               const bf16* __restrict__ W,
                                               int N, int K, EpA ep) {
  __shared__ __align__(16) bf16 As[128 * 64];
  __shared__ __align__(16) bf16 Bs[128 * 64];
  const int t = threadIdx.x;
  const int lane = t & 63;
  const int wv = t >> 6;
  const int wm = wv >> 1, wn = wv & 1;
  const int quad = lane >> 4, l16 = lane & 15;
  const int bm = blockIdx.x << 7, bn = blockIdx.y << 7;

  f32x4 acc[4][4] = {};

  for (int k0 = 0; k0 < K; k0 += 64) {
    __syncthreads();
#pragma unroll
    for (int i = 0; i < 4; ++i) {
      int slot = i * 256 + t;
      int m = slot >> 3;
      int lk8 = (slot & 7) ^ (m & 7);  // logical k8 stored at physical slot
      gl_lds16(A + (size_t)(bm + m) * K + k0 + lk8 * 8, As + slot * 8);
      gl_lds16(W + (size_t)(bn + m) * K + k0 + lk8 * 8, Bs + slot * 8);
    }
    __syncthreads();
#pragma unroll
    for (int ks = 0; ks < 2; ++ks) {
      short8 af[4], bfr[4];
#pragma unroll
      for (int i = 0; i < 4; ++i) {
        int m = wm * 64 + i * 16 + l16;
        int pa = (ks * 4 + quad) ^ (m & 7);
        af[i] = *(const short8*)(As + m * 64 + pa * 8);
        int n = wn * 64 + i * 16 + l16;
        int pb = (ks * 4 + quad) ^ (n & 7);
        bfr[i] = *(const short8*)(Bs + n * 64 + pb * 8);
      }
#pragma unroll
      for (int i = 0; i < 4; ++i)
#pragma unroll
        for (int j = 0; j < 4; ++j)
          acc[i][j] = __builtin_amdgcn_mfma_f32_16x16x32_bf16(af[i], bfr[j], acc[i][j], 0, 0, 0);
    }
  }

  // epilogue: C row=(lane>>4)*4+r, col=lane&15 (verified m89/m91)
#pragma unroll
  for (int i = 0; i < 4; ++i) {
#pragma unroll
    for (int j = 0; j < 4; ++j) {
#pragma unroll
      for (int r = 0; r < 4; ++r) {
        int m = bm + wm * 64 + i * 16 + quad * 4 + r;
        int n = bn + wn * 64 + j * 16 + l16;
        size_t idx = (size_t)m * N + n;
        float v = acc[i][j][r];
        if (EP == 1) {         // gate + plugback (N == DMODEL)
          float g = sigm(v + ep.bias[n]);
          float pm = ep.p[m];
          int bb = m >> 11;
          float sm = ep.smoothed[((size_t)(bb * NM + ep.bucket[m])) * DMODEL + n];
          float e = __bfloat162float(ep.encb[idx]);
          ep.outb[idx] = __float2bfloat16((1.f - pm) * g * e + sm);
        } else if (EP == 3) {  // r_t -> a_t (f32)
          float rr = sigm(v + ep.bias[n]);
          ep.outf[idx] = exp2f(rr * ep.e8l2a[n]);
        } else if (EP == 4) {  // i_t -> s_t = sqrt(1-a^2)*i*xconv (bf16)
          float ii = sigm(v + ep.bias[n]);
          float u = ii * __bfloat162float(ep.xconvb[idx]);
          float a = ep.abuf[idx];
          ep.outb[idx] = __float2bfloat16(sqrtf(fmaxf(1.f - a * a, 0.f)) * u);
        } else {               // EP == 5: plain bf16 out
          ep.outb[idx] = __float2bfloat16(v);
        }
      }
    }
  }
}

// ---------------- launch ----------------

extern "C" void kernel_launch(void* const* d_in, const int* in_sizes, int n_in,
                              void* d_out, int out_size, void* d_ws, size_t ws_size,
                              hipStream_t stream) {
  const float* concept_out = (const float*)d_in[0];
  const float* encoder_out = (const float*)d_in[1];
  const float* bprobs      = (const float*)d_in[2];
  const int*   bidx        = (const int*)d_in[3];
  const float* gate_w      = (const float*)d_in[4];
  const float* gate_b      = (const float*)d_in[5];
  const float* down_w      = (const float*)d_in[6];
  const float* up_w        = (const float*)d_in[7];
  const float* norm_out_w  = (const float*)d_in[8];
  const float* rc_w        = (const float*)d_in[9];
  const float* rc_b        = (const float*)d_in[10];
  const float* wr_w        = (const float*)d_in[11];
  const float* wr_b        = (const float*)d_in[12];
  const float* wi_w        = (const float*)d_in[13];
  const float* wi_b        = (const float*)d_in[14];
  const float* log_a       = (const float*)d_in[15];
  const float* ow_w        = (const float*)d_in[16];
  const float* rn_w        = (const float*)d_in[17];
  float* out = (float*)d_out;
  (void)in_sizes; (void)n_in; (void)out_size; (void)ws_size;

  // workspace arena
  char* base = (char*)d_ws;
  size_t off = 0;
  auto alloc = [&](size_t bytes) -> char* {
    char* p = base + off;
    off += (bytes + 255) & ~(size_t)255;
    return p;
  };
  float* smoothed = (float*)alloc((size_t)NB * NM * DMODEL * 4);   // 8 MB
  int*   bucket   = (int*)alloc((size_t)BLR * 4);
  bf16*  gate_wb  = (bf16*)alloc((size_t)DMODEL * DMODEL * 2);
  bf16*  down_wb  = (bf16*)alloc((size_t)DO * DMODEL * 2);
  bf16*  up_wb    = (bf16*)alloc((size_t)DMODEL * DO * 2);
  bf16*  wrb      = (bf16*)alloc((size_t)3 * DO * DO * 2);
  bf16*  wib      = (bf16*)alloc((size_t)3 * DO * DO * 2);
  bf16*  owb      = (bf16*)alloc((size_t)3 * DO * DO * 2);
  float* e8       = (float*)alloc(3 * DO * 4);
  float* Ac       = (float*)alloc((size_t)NB * NCH * DO * 4);
  float* Sc       = (float*)alloc((size_t)NB * NCH * DO * 4);
  float* Hin      = (float*)alloc((size_t)NB * NCH * DO * 4);
  bf16*  xb       = (bf16*)alloc((size_t)BLR * DO * 2);            // 8 MB (layer input x, bf16)
  char*  RA       = alloc(80ull << 20);                            // reused region
  // phase 1 overlays
  bf16*  encb = (bf16*)RA;                          // 32 MB (dead after G1)
  bf16*  h0b  = (bf16*)(RA + (32ull << 20));        // 32 MB (dead after G2)
  // layer overlays
  bf16*  xconvb = (bf16*)RA;                        //  8 MB
  float* abuf   = (float*)(RA + (8ull << 20));      // 16 MB (a_t stays f32: 1-a ~ 5e-3)
  bf16*  sb     = (bf16*)(RA + (24ull << 20));      //  8 MB
  bf16*  hsb    = (bf16*)(RA + (32ull << 20));      //  8 MB
  bf16*  tmpb   = (bf16*)(RA + (40ull << 20));      //  8 MB
  // final overlay
  bf16*  tmp2b  = (bf16*)RA;                        // 32 MB

  auto cvt = [&](const float* src, bf16* dst, int n) {
    cvt_bf16_kernel<<<(n + 255) / 256, 256, 0, stream>>>(src, dst, n);
  };
  cvt(encoder_out, encb, BLR * DMODEL);
  cvt(gate_w, gate_wb, DMODEL * DMODEL);
  cvt(down_w, down_wb, DO * DMODEL);
  cvt(up_w, up_wb, DMODEL * DO);
  cvt(wr_w, wrb, 3 * DO * DO);
  cvt(wi_w, wib, 3 * DO * DO);
  cvt(ow_w, owb, 3 * DO * DO);
  e8l2a_kernel<<<3, 256, 0, stream>>>(log_a, e8, 3 * DO);
  ema_kernel<<<NB * 4, 256, 0, stream>>>(concept_out, bprobs, bidx, smoothed);
  bucket_kernel<<<BLR / 256, 256, 0, stream>>>(bidx, bucket);

  EpA ep;
  // G1: gate GEMM + fused gated residual + plugback -> h0 (bf16)
  ep = EpA{};
  ep.outb = h0b; ep.bias = gate_b; ep.encb = encb; ep.p = bprobs;
  ep.bucket = bucket; ep.smoothed = smoothed;
  gemm_bt<1><<<dim3(BLR / 128, DMODEL / 128), 256, 0, stream>>>(encb, gate_wb, DMODEL, DMODEL, ep);
  // G2: down projection -> x (bf16)
  ep = EpA{}; ep.outb = xb;
  gemm_bt<5><<<dim3(BLR / 128, DO / 128), 256, 0, stream>>>(h0b, down_wb, DO, DMODEL, ep);

  for (int k = 0; k < 3; ++k) {
    conv_kernel<<<BLR, 256, 0, stream>>>(xb, rc_w + k * DO * 4, rc_b + k * DO, xconvb);
    ep = EpA{}; ep.outf = abuf; ep.bias = wr_b + k * DO; ep.e8l2a = e8 + k * DO;
    gemm_bt<3><<<dim3(BLR / 128, DO / 128), 256, 0, stream>>>(xconvb, wrb + k * DO * DO, DO, DO, ep);
    ep = EpA{}; ep.outb = sb; ep.bias = wi_b + k * DO; ep.xconvb = xconvb; ep.abuf = abuf;
    gemm_bt<4><<<dim3(BLR / 128, DO / 128), 256, 0, stream>>>(xconvb, wib + k * DO * DO, DO, DO, ep);
    scan1_kernel<<<NB * NCH, 256, 0, stream>>>(abuf, sb, Ac, Sc);
    scan2_kernel<<<NB, 256, 0, stream>>>(Ac, Sc, Hin);
    scan3_kernel<<<NB * NCH, 256, 0, stream>>>(abuf, sb, Hin, hsb);
    ep = EpA{}; ep.outb = tmpb;
    gemm_bt<5><<<dim3(BLR / 128, DO / 128), 256, 0, stream>>>(hsb, owb + k * DO * DO, DO, DO, ep);
    rmsnorm256_kernel<<<BLR, 256, 0, stream>>>(tmpb, rn_w + k * DO, xb);
  }

  // G6: up projection -> tmp2 (bf16), then final rmsnorm -> out (f32)
  ep = EpA{}; ep.outb = tmp2b;
  gemm_bt<5><<<dim3(BLR / 128, DMODEL / 128), 256, 0, stream>>>(xb, up_wb, DMODEL, DO, ep);
  rmsnorm1024_kernel<<<BLR, 256, 0, stream>>>(tmp2b, norm_out_w, out);
}

// Round 3
// 645.972 us; speedup vs baseline: 1.0699x; 1.0284x over previous
//
#include <hip/hip_runtime.h>
#include <hip/hip_bf16.h>
#include <stdint.h>

typedef __attribute__((ext_vector_type(8))) short short8;   // 8 bf16 (4 VGPRs)
typedef __attribute__((ext_vector_type(4))) float f32x4;    // 4 fp32 acc
typedef __hip_bfloat16 bf16;

#define NB   8
#define LSEQ 2048
#define NM   256
#define DMODEL 1024
#define DO   256
#define BLR  16384   /* NB*LSEQ rows */

__device__ __forceinline__ float sigm(float x) { return 1.f / (1.f + __expf(-x)); }

__device__ __forceinline__ void gl_lds16(const void* g, void* l) {
  __builtin_amdgcn_global_load_lds((const __attribute__((address_space(1))) void*)g,
                                   (__attribute__((address_space(3))) void*)l, 16, 0, 0);
}

__device__ __forceinline__ unsigned short bf16bits(float v) {
  bf16 b = __float2bfloat16(v);
  return *(unsigned short*)&b;
}

// ---------------- prep: all weight cvts + e8l2a in ONE dispatch ----------------

__global__ __launch_bounds__(256) void prep_kernel(
    const float* __restrict__ gate_w, const float* __restrict__ down_w,
    const float* __restrict__ up_w, const float* __restrict__ wr_w,
    const float* __restrict__ wi_w, const float* __restrict__ ow_w,
    const float* __restrict__ log_a,
    bf16* __restrict__ gate_wb, bf16* __restrict__ down_wb, bf16* __restrict__ up_wb,
    bf16* __restrict__ wrb, bf16* __restrict__ wib, bf16* __restrict__ owb,
    float* __restrict__ e8) {
  int i = blockIdx.x * 256 + threadIdx.x;
  if (i < 1048576) { gate_wb[i] = __float2bfloat16(gate_w[i]); return; }
  i -= 1048576;
  if (i < 262144) { down_wb[i] = __float2bfloat16(down_w[i]); return; }
  i -= 262144;
  if (i < 262144) { up_wb[i] = __float2bfloat16(up_w[i]); return; }
  i -= 262144;
  if (i < 196608) { wrb[i] = __float2bfloat16(wr_w[i]); return; }
  i -= 196608;
  if (i < 196608) { wib[i] = __float2bfloat16(wi_w[i]); return; }
  i -= 196608;
  if (i < 196608) { owb[i] = __float2bfloat16(ow_w[i]); return; }
  i -= 196608;
  if (i < 768) {
    float ab = 1.f / (1.f + expf(-log_a[i]));
    e8[i] = 8.f * log2f(ab);
  }
}

// vectorized f32 -> bf16 (4 elem/thread)
__global__ __launch_bounds__(256) void cvt4_kernel(const float4* __restrict__ in,
                                                   ushort4* __restrict__ out, int n4) {
  int i = blockIdx.x * 256 + threadIdx.x;
  if (i < n4) {
    float4 v = in[i];
    ushort4 o;
    o.x = bf16bits(v.x); o.y = bf16bits(v.y); o.z = bf16bits(v.z); o.w = bf16bits(v.w);
    out[i] = o;
  }
}

// ---------------- EMA + bucket ----------------

__global__ __launch_bounds__(256) void ema_kernel(const float* __restrict__ cpt,
                                                  const float* __restrict__ bprobs,
                                                  const int* __restrict__ bidx,
                                                  float* __restrict__ smoothed) {
  int b = blockIdx.x >> 2;
  int c = ((blockIdx.x & 3) << 8) + threadIdx.x;
  __shared__ float p[NM];
  p[threadIdx.x] = bprobs[b * LSEQ + bidx[b * NM + threadIdx.x]];
  __syncthreads();
  const float* cp = cpt + (size_t)b * NM * DMODEL + c;
  float* sp = smoothed + (size_t)b * NM * DMODEL + c;
  float h = 0.f;
  for (int m = 0; m < NM; ++m) {
    float pm = p[m];
    h = pm * cp[(size_t)m * DMODEL] + (1.f - pm) * h;
    sp[(size_t)m * DMODEL] = h;
  }
}

__global__ __launch_bounds__(256) void bucket_kernel(const int* __restrict__ bidx,
                                                     int* __restrict__ bucket) {
  int i = blockIdx.x * 256 + threadIdx.x;
  int b = i >> 11, l = i & 2047;
  const int* bi = bidx + b * NM;
  int lo = 0, hi = NM;
  while (lo < hi) {
    int mid = (lo + hi) >> 1;
    if (bi[mid] <= l) lo = mid + 1; else hi = mid;
  }
  int v = lo - 1;
  bucket[i] = v < 0 ? 0 : v;
}

// ---------------- depthwise causal conv k=4 ----------------

__global__ __launch_bounds__(256) void conv_kernel(const bf16* __restrict__ x,
                                                   const float* __restrict__ cw,
                                                   const float* __restrict__ cb,
                                                   bf16* __restrict__ xcb) {
  int i = blockIdx.x * 256 + threadIdx.x;
  int c = i & 255;
  int bl = i >> 8;
  int l = bl & 2047;
  float4 w4 = ((const float4*)cw)[c];
  const float* wf = (const float*)&w4;
  float s = cb[c];
#pragma unroll
  for (int kk = 0; kk < 4; ++kk) {
    int ll = l - 3 + kk;
    if (ll >= 0) s += wf[kk] * __bfloat162float(x[i + (kk - 3) * 256]);
  }
  xcb[i] = __float2bfloat16(s);
}

// ---------------- single-dispatch full-sequence scan: h = a*h + s ----------------
// as[t][c] = float2{a, s}; one wave owns (b, 64-channel group), software-pipelined.

__global__ __launch_bounds__(64) void scan_kernel(const float2* __restrict__ as,
                                                  bf16* __restrict__ hs) {
  int b = blockIdx.x >> 2, cg = blockIdx.x & 3;
  int c = (cg << 6) + threadIdx.x;
  size_t base = (size_t)b * LSEQ * DO + c;
  constexpr int U = 16;
  float2 A[U], Bv[U];
#pragma unroll
  for (int u = 0; u < U; ++u) A[u] = as[base + (size_t)u * DO];
  float h = 0.f;
  for (int t0 = 0; t0 < LSEQ; t0 += 2 * U) {
    if (t0 + U < LSEQ) {
#pragma unroll
      for (int u = 0; u < U; ++u) Bv[u] = as[base + (size_t)(t0 + U + u) * DO];
    }
#pragma unroll
    for (int u = 0; u < U; ++u) {
      h = A[u].x * h + A[u].y;
      hs[base + (size_t)(t0 + u) * DO] = __float2bfloat16(h);
    }
    if (t0 + 2 * U < LSEQ) {
#pragma unroll
      for (int u = 0; u < U; ++u) A[u] = as[base + (size_t)(t0 + 2 * U + u) * DO];
    }
#pragma unroll
    for (int u = 0; u < U; ++u) {
      h = Bv[u].x * h + Bv[u].y;
      hs[base + (size_t)(t0 + U + u) * DO] = __float2bfloat16(h);
    }
  }
}

// ---------------- final rmsnorm over 1024, bf16 in -> f32 out ----------------

__global__ __launch_bounds__(256) void rmsnorm1024_kernel(const bf16* __restrict__ in,
                                                          const float* __restrict__ w,
                                                          float* __restrict__ out) {
  int row = blockIdx.x, t = threadIdx.x;
  ushort4 raw = ((const ushort4*)(in + (size_t)row * 1024))[t];
  float v0 = __bfloat162float(*(const bf16*)&raw.x);
  float v1 = __bfloat162float(*(const bf16*)&raw.y);
  float v2 = __bfloat162float(*(const bf16*)&raw.z);
  float v3 = __bfloat162float(*(const bf16*)&raw.w);
  float ss = v0 * v0 + v1 * v1 + v2 * v2 + v3 * v3;
#pragma unroll
  for (int ofs = 32; ofs > 0; ofs >>= 1) ss += __shfl_down(ss, ofs, 64);
  __shared__ float wsum[4];
  if ((t & 63) == 0) wsum[t >> 6] = ss;
  __syncthreads();
  float tot = wsum[0] + wsum[1] + wsum[2] + wsum[3];
  float sc = rsqrtf(tot * (1.f / 1024.f) + 1e-6f);
  float4 wv = ((const float4*)w)[t];
  float4 o;
  o.x = v0 * sc * wv.x; o.y = v1 * sc * wv.y;
  o.z = v2 * sc * wv.z; o.w = v3 * sc * wv.w;
  ((float4*)(out + (size_t)row * 1024))[t] = o;
}

// ---------------- generic MFMA GEMM 128x128 (EP1 gate-fused, EP5 plain) ----------------

struct EpA {
  bf16* outb;
  const float* bias;
  const bf16* encb;
  const float* p;
  const int* bucket;
  const float* smoothed;
};

template <int EP>
__global__ __launch_bounds__(256) void gemm_bt(const bf16* __restrict__ A,
                                               const bf16* __restrict__ W,
                                               int N, int K, EpA ep) {
  __shared__ __align__(16) bf16 As[128 * 64];
  __shared__ __align__(16) bf16 Bs[128 * 64];
  const int t = threadIdx.x;
  const int lane = t & 63;
  const int wv = t >> 6;
  const int wm = wv >> 1, wn = wv & 1;
  const int quad = lane >> 4, l16 = lane & 15;
  const int bm = blockIdx.x << 7, bn = blockIdx.y << 7;

  f32x4 acc[4][4] = {};

  for (int k0 = 0; k0 < K; k0 += 64) {
    __syncthreads();
#pragma unroll
    for (int i = 0; i < 4; ++i) {
      int slot = i * 256 + t;
      int m = slot >> 3;
      int lk8 = (slot & 7) ^ (m & 7);
      gl_lds16(A + (size_t)(bm + m) * K + k0 + lk8 * 8, As + slot * 8);
      gl_lds16(W + (size_t)(bn + m) * K + k0 + lk8 * 8, Bs + slot * 8);
    }
    __syncthreads();
#pragma unroll
    for (int ks = 0; ks < 2; ++ks) {
      short8 af[4], bfr[4];
#pragma unroll
      for (int i = 0; i < 4; ++i) {
        int m = wm * 64 + i * 16 + l16;
        int pa = (ks * 4 + quad) ^ (m & 7);
        af[i] = *(const short8*)(As + m * 64 + pa * 8);
        int n = wn * 64 + i * 16 + l16;
        int pb = (ks * 4 + quad) ^ (n & 7);
        bfr[i] = *(const short8*)(Bs + n * 64 + pb * 8);
      }
#pragma unroll
      for (int i = 0; i < 4; ++i)
#pragma unroll
        for (int j = 0; j < 4; ++j)
          acc[i][j] = __builtin_amdgcn_mfma_f32_16x16x32_bf16(af[i], bfr[j], acc[i][j], 0, 0, 0);
    }
  }

#pragma unroll
  for (int i = 0; i < 4; ++i) {
#pragma unroll
    for (int j = 0; j < 4; ++j) {
#pragma unroll
      for (int r = 0; r < 4; ++r) {
        int m = bm + wm * 64 + i * 16 + quad * 4 + r;
        int n = bn + wn * 64 + j * 16 + l16;
        size_t idx = (size_t)m * N + n;
        float v = acc[i][j][r];
        if (EP == 1) {         // gate + plugback (N == DMODEL)
          float g = sigm(v + ep.bias[n]);
          float pm = ep.p[m];
          int bb = m >> 11;
          float sm = ep.smoothed[((size_t)(bb * NM + ep.bucket[m])) * DMODEL + n];
          float e = __bfloat162float(ep.encb[idx]);
          ep.outb[idx] = __float2bfloat16((1.f - pm) * g * e + sm);
        } else {               // EP == 5: plain bf16 out
          ep.outb[idx] = __float2bfloat16(v);
        }
      }
    }
  }
}

// ---------------- dual GEMM: r & i heads share A, fused a_t/s_t epilogue ----------------
// A = xconv bf16 [BLR,256]; Wr,Wi [256,256]. Writes packed float2{a, s}.

__global__ __launch_bounds__(256) void gemm_ri(const bf16* __restrict__ A,
                                               const bf16* __restrict__ Wr,
                                               const bf16* __restrict__ Wi,
                                               const float* __restrict__ rbias,
                                               const float* __restrict__ ibias,
                                               const float* __restrict__ e8,
                                               float2* __restrict__ as_out) {
  __shared__ __align__(16) bf16 As[128 * 64];
  __shared__ __align__(16) bf16 Br[128 * 64];
  __shared__ __align__(16) bf16 Bi[128 * 64];
  const int t = threadIdx.x;
  const int lane = t & 63;
  const int wv = t >> 6;
  const int wm = wv >> 1, wn = wv & 1;
  const int quad = lane >> 4, l16 = lane & 15;
  const int bm = blockIdx.x << 7, bn = blockIdx.y << 7;

  f32x4 ar[4][4] = {};
  f32x4 ai[4][4] = {};

  for (int k0 = 0; k0 < DO; k0 += 64) {
    __syncthreads();
#pragma unroll
    for (int i = 0; i < 4; ++i) {
      int slot = i * 256 + t;
      int m = slot >> 3;
      int lk8 = (slot & 7) ^ (m & 7);
      gl_lds16(A + (size_t)(bm + m) * DO + k0 + lk8 * 8, As + slot * 8);
      gl_lds16(Wr + (size_t)(bn + m) * DO + k0 + lk8 * 8, Br + slot * 8);
      gl_lds16(Wi + (size_t)(bn + m) * DO + k0 + lk8 * 8, Bi + slot * 8);
    }
    __syncthreads();
#pragma unroll
    for (int ks = 0; ks < 2; ++ks) {
      short8 af[4], br[4], bi[4];
#pragma unroll
      for (int i = 0; i < 4; ++i) {
        int m = wm * 64 + i * 16 + l16;
        int pa = (ks * 4 + quad) ^ (m & 7);
        af[i] = *(const short8*)(As + m * 64 + pa * 8);
        int n = wn * 64 + i * 16 + l16;
        int pb = (ks * 4 + quad) ^ (n & 7);
        br[i] = *(const short8*)(Br + n * 64 + pb * 8);
        bi[i] = *(const short8*)(Bi + n * 64 + pb * 8);
      }
#pragma unroll
      for (int i = 0; i < 4; ++i)
#pragma unroll
        for (int j = 0; j < 4; ++j) {
          ar[i][j] = __builtin_amdgcn_mfma_f32_16x16x32_bf16(af[i], br[j], ar[i][j], 0, 0, 0);
          ai[i][j] = __builtin_amdgcn_mfma_f32_16x16x32_bf16(af[i], bi[j], ai[i][j], 0, 0, 0);
        }
    }
  }

#pragma unroll
  for (int i = 0; i < 4; ++i) {
#pragma unroll
    for (int j = 0; j < 4; ++j) {
#pragma unroll
      for (int r = 0; r < 4; ++r) {
        int m = bm + wm * 64 + i * 16 + quad * 4 + r;
        int n = bn + wn * 64 + j * 16 + l16;
        size_t idx = (size_t)m * DO + n;
        float rv = sigm(ar[i][j][r] + rbias[n]);
        float a = exp2f(rv * e8[n]);
        float iv = sigm(ai[i][j][r] + ibias[n]);
        float xc = __bfloat162float(A[idx]);            // xconv[m][n] == A[m][n]
        float s = sqrtf(fmaxf(1.f - a * a, 0.f)) * iv * xc;
        as_out[idx] = make_float2(a, s);
      }
    }
  }
}

// ---------------- out-proj GEMM tile 64x256 + fused RMSNorm(256) ----------------

__global__ __launch_bounds__(256) void gemm_on(const bf16* __restrict__ A,   // hs [BLR,256]
                                               const bf16* __restrict__ W,   // ow [256,256]
                                               const float* __restrict__ rnw,
                                               bf16* __restrict__ xb) {
  __shared__ __align__(16) bf16 As[64 * 64];
  __shared__ __align__(16) bf16 Bs[256 * 64];
  __shared__ float red[4][64];
  const int t = threadIdx.x;
  const int lane = t & 63;
  const int wn = t >> 6;           // wave = column slice of 64
  const int quad = lane >> 4, l16 = lane & 15;
  const int bm = blockIdx.x << 6;

  f32x4 acc[4][4] = {};

  for (int k0 = 0; k0 < DO; k0 += 64) {
    __syncthreads();
#pragma unroll
    for (int i = 0; i < 2; ++i) {
      int slot = i * 256 + t;
      int m = slot >> 3;
      int lk8 = (slot & 7) ^ (m & 7);
      gl_lds16(A + (size_t)(bm + m) * DO + k0 + lk8 * 8, As + slot * 8);
    }
#pragma unroll
    for (int i = 0; i < 8; ++i) {
      int slot = i * 256 + t;
      int n = slot >> 3;
      int lk8 = (slot & 7) ^ (n & 7);
      gl_lds16(W + (size_t)n * DO + k0 + lk8 * 8, Bs + slot * 8);
    }
    __syncthreads();
#pragma unroll
    for (int ks = 0; ks < 2; ++ks) {
      short8 af[4], bfr[4];
#pragma unroll
      for (int i = 0; i < 4; ++i) {
        int m = i * 16 + l16;
        int pa = (ks * 4 + quad) ^ (m & 7);
        af[i] = *(const short8*)(As + m * 64 + pa * 8);
        int n = wn * 64 + i * 16 + l16;
        int pb = (ks * 4 + quad) ^ (n & 7);
        bfr[i] = *(const short8*)(Bs + n * 64 + pb * 8);
      }
#pragma unroll
      for (int i = 0; i < 4; ++i)
#pragma unroll
        for (int j = 0; j < 4; ++j)
          acc[i][j] = __builtin_amdgcn_mfma_f32_16x16x32_bf16(af[i], bfr[j], acc[i][j], 0, 0, 0);
    }
  }

  // fused rmsnorm: row sums of squares (this wave's 64 cols), then LDS combine
  float part[4][4];
#pragma unroll
  for (int i = 0; i < 4; ++i)
#pragma unroll
    for (int r = 0; r < 4; ++r) {
      float s = 0.f;
#pragma unroll
      for (int j = 0; j < 4; ++j) s += acc[i][j][r] * acc[i][j][r];
      part[i][r] = s;
    }
#pragma unroll
  for (int mask = 1; mask <= 8; mask <<= 1)
#pragma unroll
    for (int i = 0; i < 4; ++i)
#pragma unroll
      for (int r = 0; r < 4; ++r) part[i][r] += __shfl_xor(part[i][r], mask, 64);
  if (l16 == 0) {
#pragma unroll
    for (int i = 0; i < 4; ++i)
#pragma unroll
      for (int r = 0; r < 4; ++r) red[wn][i * 16 + quad * 4 + r] = part[i][r];
  }
  __syncthreads();
#pragma unroll
  for (int i = 0; i < 4; ++i) {
#pragma unroll
    for (int r = 0; r < 4; ++r) {
      int ml = i * 16 + quad * 4 + r;
      float tot = red[0][ml] + red[1][ml] + red[2][ml] + red[3][ml];
      float sc = rsqrtf(tot * (1.f / 256.f) + 1e-6f);
#pragma unroll
      for (int j = 0; j < 4; ++j) {
        int n = wn * 64 + j * 16 + l16;
        xb[(size_t)(bm + ml) * DO + n] = __float2bfloat16(acc[i][j][r] * sc * rnw[n]);
      }
    }
  }
}

// ---------------- launch ----------------

extern "C" void kernel_launch(void* const* d_in, const int* in_sizes, int n_in,
                              void* d_out, int out_size, void* d_ws, size_t ws_size,
                              hipStream_t stream) {
  const float* concept_out = (const float*)d_in[0];
  const float* encoder_out = (const float*)d_in[1];
  const float* bprobs      = (const float*)d_in[2];
  const int*   bidx        = (const int*)d_in[3];
  const float* gate_w      = (const float*)d_in[4];
  const float* gate_b      = (const float*)d_in[5];
  const float* down_w      = (const float*)d_in[6];
  const float* up_w        = (const float*)d_in[7];
  const float* norm_out_w  = (const float*)d_in[8];
  const float* rc_w        = (const float*)d_in[9];
  const float* rc_b        = (const float*)d_in[10];
  const float* wr_w        = (const float*)d_in[11];
  const float* wr_b        = (const float*)d_in[12];
  const float* wi_w        = (const float*)d_in[13];
  const float* wi_b        = (const float*)d_in[14];
  const float* log_a       = (const float*)d_in[15];
  const float* ow_w        = (const float*)d_in[16];
  const float* rn_w        = (const float*)d_in[17];
  float* out = (float*)d_out;
  (void)in_sizes; (void)n_in; (void)out_size; (void)ws_size;

  char* base = (char*)d_ws;
  size_t off = 0;
  auto alloc = [&](size_t bytes) -> char* {
    char* p = base + off;
    off += (bytes + 255) & ~(size_t)255;
    return p;
  };
  float* smoothed = (float*)alloc((size_t)NB * NM * DMODEL * 4);   // 8 MB
  int*   bucket   = (int*)alloc((size_t)BLR * 4);
  bf16*  gate_wb  = (bf16*)alloc((size_t)DMODEL * DMODEL * 2);
  bf16*  down_wb  = (bf16*)alloc((size_t)DO * DMODEL * 2);
  bf16*  up_wb    = (bf16*)alloc((size_t)DMODEL * DO * 2);
  bf16*  wrb      = (bf16*)alloc((size_t)3 * DO * DO * 2);
  bf16*  wib      = (bf16*)alloc((size_t)3 * DO * DO * 2);
  bf16*  owb      = (bf16*)alloc((size_t)3 * DO * DO * 2);
  float* e8       = (float*)alloc(3 * DO * 4);
  bf16*  xb       = (bf16*)alloc((size_t)BLR * DO * 2);            // 8 MB layer io
  char*  RA       = alloc(64ull << 20);                            // reused region
  // head overlays
  bf16*  encb = (bf16*)RA;                          // 32 MB (dead after G1)
  bf16*  h0b  = (bf16*)(RA + (32ull << 20));        // 32 MB (dead after G2)
  // layer overlays
  bf16*   xconvb = (bf16*)RA;                       //  8 MB
  float2* asbuf  = (float2*)(RA + (8ull << 20));    // 32 MB packed {a,s}
  bf16*   hsb    = (bf16*)(RA + (40ull << 20));     //  8 MB
  // tail overlay
  bf16*  tmp2b  = (bf16*)RA;                        // 32 MB

  cvt4_kernel<<<(BLR * DMODEL / 4 + 255) / 256, 256, 0, stream>>>(
      (const float4*)encoder_out, (ushort4*)encb, BLR * DMODEL / 4);
  prep_kernel<<<(2163456 + 255) / 256, 256, 0, stream>>>(
      gate_w, down_w, up_w, wr_w, wi_w, ow_w, log_a,
      gate_wb, down_wb, up_wb, wrb, wib, owb, e8);
  ema_kernel<<<NB * 4, 256, 0, stream>>>(concept_out, bprobs, bidx, smoothed);
  bucket_kernel<<<BLR / 256, 256, 0, stream>>>(bidx, bucket);

  EpA ep;
  // G1: gate GEMM + fused gated residual + plugback -> h0 (bf16)
  ep = EpA{};
  ep.outb = h0b; ep.bias = gate_b; ep.encb = encb; ep.p = bprobs;
  ep.bucket = bucket; ep.smoothed = smoothed;
  gemm_bt<1><<<dim3(BLR / 128, DMODEL / 128), 256, 0, stream>>>(encb, gate_wb, DMODEL, DMODEL, ep);
  // G2: down projection -> xb (bf16)
  ep = EpA{}; ep.outb = xb;
  gemm_bt<5><<<dim3(BLR / 128, DO / 128), 256, 0, stream>>>(h0b, down_wb, DO, DMODEL, ep);

  for (int k = 0; k < 3; ++k) {
    conv_kernel<<<BLR, 256, 0, stream>>>(xb, rc_w + k * DO * 4, rc_b + k * DO, xconvb);
    gemm_ri<<<dim3(BLR / 128, DO / 128), 256, 0, stream>>>(
        xconvb, wrb + k * DO * DO, wib + k * DO * DO,
        wr_b + k * DO, wi_b + k * DO, e8 + k * DO, asbuf);
    scan_kernel<<<NB * 4, 64, 0, stream>>>(asbuf, hsb);
    gemm_on<<<BLR / 64, 256, 0, stream>>>(hsb, owb + k * DO * DO, rn_w + k * DO, xb);
  }

  // up projection -> tmp2 (bf16), final rmsnorm -> out (f32)
  ep = EpA{}; ep.outb = tmp2b;
  gemm_bt<5><<<dim3(BLR / 128, DMODEL / 128), 256, 0, stream>>>(xb, up_wb, DMODEL, DO, ep);
  rmsnorm1024_kernel<<<BLR, 256, 0, stream>>>(tmp2b, norm_out_w, out);
}

// Round 5
// 535.001 us; speedup vs baseline: 1.2918x; 1.2074x over previous
//
#include <hip/hip_runtime.h>
#include <hip/hip_bf16.h>
#include <stdint.h>

typedef __attribute__((ext_vector_type(8))) short short8;   // 8 bf16 (4 VGPRs)
typedef __attribute__((ext_vector_type(4))) float f32x4;    // 4 fp32 acc
typedef __hip_bfloat16 bf16;

#define NB   8
#define LSEQ 2048
#define NM   256
#define DMODEL 1024
#define DO   256
#define BLR  16384   /* NB*LSEQ rows */
#define NCH  32      /* scan chunks */
#define CLK  64      /* chunk length */

__device__ __forceinline__ float sigm(float x) { return 1.f / (1.f + __expf(-x)); }

__device__ __forceinline__ void gl_lds16(const void* g, void* l) {
  __builtin_amdgcn_global_load_lds((const __attribute__((address_space(1))) void*)g,
                                   (__attribute__((address_space(3))) void*)l, 16, 0, 0);
}

__device__ __forceinline__ unsigned short bf16bits(float v) {
  bf16 b = __float2bfloat16(v);
  return *(unsigned short*)&b;
}
__device__ __forceinline__ float bits2f(unsigned short u) {
  bf16 b = *(bf16*)&u;
  return __bfloat162float(b);
}

// ---------------- prep: all weight cvts + e8l2a in ONE dispatch ----------------

__global__ __launch_bounds__(256) void prep_kernel(
    const float* __restrict__ gate_w, const float* __restrict__ down_w,
    const float* __restrict__ up_w, const float* __restrict__ wr_w,
    const float* __restrict__ wi_w, const float* __restrict__ ow_w,
    const float* __restrict__ log_a,
    bf16* __restrict__ gate_wb, bf16* __restrict__ down_wb, bf16* __restrict__ up_wb,
    bf16* __restrict__ wrb, bf16* __restrict__ wib, bf16* __restrict__ owb,
    float* __restrict__ e8) {
  int i = blockIdx.x * 256 + threadIdx.x;
  if (i < 1048576) { gate_wb[i] = __float2bfloat16(gate_w[i]); return; }
  i -= 1048576;
  if (i < 262144) { down_wb[i] = __float2bfloat16(down_w[i]); return; }
  i -= 262144;
  if (i < 262144) { up_wb[i] = __float2bfloat16(up_w[i]); return; }
  i -= 262144;
  if (i < 196608) { wrb[i] = __float2bfloat16(wr_w[i]); return; }
  i -= 196608;
  if (i < 196608) { wib[i] = __float2bfloat16(wi_w[i]); return; }
  i -= 196608;
  if (i < 196608) { owb[i] = __float2bfloat16(ow_w[i]); return; }
  i -= 196608;
  if (i < 768) {
    float ab = 1.f / (1.f + expf(-log_a[i]));
    e8[i] = 8.f * log2f(ab);
  }
}

// vectorized f32 -> bf16 (4 elem/thread)
__global__ __launch_bounds__(256) void cvt4_kernel(const float4* __restrict__ in,
                                                   ushort4* __restrict__ out, int n4) {
  int i = blockIdx.x * 256 + threadIdx.x;
  if (i < n4) {
    float4 v = in[i];
    ushort4 o;
    o.x = bf16bits(v.x); o.y = bf16bits(v.y); o.z = bf16bits(v.z); o.w = bf16bits(v.w);
    out[i] = o;
  }
}

// ---------------- EMA + bucket ----------------

__global__ __launch_bounds__(256) void ema_kernel(const float* __restrict__ cpt,
                                                  const float* __restrict__ bprobs,
                                                  const int* __restrict__ bidx,
                                                  float* __restrict__ smoothed) {
  int b = blockIdx.x >> 2;
  int c = ((blockIdx.x & 3) << 8) + threadIdx.x;
  __shared__ float p[NM];
  p[threadIdx.x] = bprobs[b * LSEQ + bidx[b * NM + threadIdx.x]];
  __syncthreads();
  const float* cp = cpt + (size_t)b * NM * DMODEL + c;
  float* sp = smoothed + (size_t)b * NM * DMODEL + c;
  float h = 0.f;
  for (int m = 0; m < NM; ++m) {
    float pm = p[m];
    h = pm * cp[(size_t)m * DMODEL] + (1.f - pm) * h;
    sp[(size_t)m * DMODEL] = h;
  }
}

__global__ __launch_bounds__(256) void bucket_kernel(const int* __restrict__ bidx,
                                                     int* __restrict__ bucket) {
  int i = blockIdx.x * 256 + threadIdx.x;
  int b = i >> 11, l = i & 2047;
  const int* bi = bidx + b * NM;
  int lo = 0, hi = NM;
  while (lo < hi) {
    int mid = (lo + hi) >> 1;
    if (bi[mid] <= l) lo = mid + 1; else hi = mid;
  }
  int v = lo - 1;
  bucket[i] = v < 0 ? 0 : v;
}

// ---------------- depthwise causal conv k=4 ----------------

__global__ __launch_bounds__(256) void conv_kernel(const bf16* __restrict__ x,
                                                   const float* __restrict__ cw,
                                                   const float* __restrict__ cb,
                                                   bf16* __restrict__ xcb) {
  int i = blockIdx.x * 256 + threadIdx.x;
  int c = i & 255;
  int bl = i >> 8;
  int l = bl & 2047;
  float4 w4 = ((const float4*)cw)[c];
  const float* wf = (const float*)&w4;
  float s = cb[c];
#pragma unroll
  for (int kk = 0; kk < 4; ++kk) {
    int ll = l - 3 + kk;
    if (ll >= 0) s += wf[kk] * __bfloat162float(x[i + (kk - 3) * 256]);
  }
  xcb[i] = __float2bfloat16(s);
}

// ---------------- chunked scan, 2 dispatches, 256 blocks each ----------------
// input packed uint: lo16 = d = 1-a (bf16), hi16 = s (bf16). h = (1-d)*h + s.

__global__ __launch_bounds__(256) void scan_p1(const unsigned int* __restrict__ ds,
                                               float2* __restrict__ AS) {
  int b = blockIdx.x >> 5, ch = blockIdx.x & 31, c = threadIdx.x;
  size_t base = ((size_t)b * LSEQ + ch * CLK) * DO + c;
  float A = 1.f, S = 0.f;
  for (int t = 0; t < CLK; ++t) {
    unsigned int u = ds[base + (size_t)t * DO];
    float d = bits2f((unsigned short)(u & 0xffff));
    float s = bits2f((unsigned short)(u >> 16));
    float a = 1.f - d;
    A *= a;
    S = __builtin_fmaf(a, S, s);
  }
  AS[blockIdx.x * DO + c] = make_float2(A, S);
}

__global__ __launch_bounds__(256) void scan_p2(const unsigned int* __restrict__ ds,
                                               const float2* __restrict__ AS,
                                               bf16* __restrict__ hs) {
  int b = blockIdx.x >> 5, ch = blockIdx.x & 31, c = threadIdx.x;
  // prefix over earlier chunks of this batch (L2-hot, <=31 iterations)
  float h = 0.f;
  for (int j = 0; j < ch; ++j) {
    float2 as = AS[(b * NCH + j) * DO + c];
    h = __builtin_fmaf(as.x, h, as.y);
  }
  size_t base = ((size_t)b * LSEQ + ch * CLK) * DO + c;
  for (int t = 0; t < CLK; ++t) {
    unsigned int u = ds[base + (size_t)t * DO];
    float d = bits2f((unsigned short)(u & 0xffff));
    float s = bits2f((unsigned short)(u >> 16));
    h = __builtin_fmaf(-d, h, h) + s;   // (1-d)*h + s
    hs[base + (size_t)t * DO] = __float2bfloat16(h);
  }
}

// ---------------- final rmsnorm over 1024, bf16 in -> f32 out ----------------

__global__ __launch_bounds__(256) void rmsnorm1024_kernel(const bf16* __restrict__ in,
                                                          const float* __restrict__ w,
                                                          float* __restrict__ out) {
  int row = blockIdx.x, t = threadIdx.x;
  ushort4 raw = ((const ushort4*)(in + (size_t)row * 1024))[t];
  float v0 = bits2f(raw.x), v1 = bits2f(raw.y), v2 = bits2f(raw.z), v3 = bits2f(raw.w);
  float ss = v0 * v0 + v1 * v1 + v2 * v2 + v3 * v3;
#pragma unroll
  for (int ofs = 32; ofs > 0; ofs >>= 1) ss += __shfl_down(ss, ofs, 64);
  __shared__ float wsum[4];
  if ((t & 63) == 0) wsum[t >> 6] = ss;
  __syncthreads();
  float tot = wsum[0] + wsum[1] + wsum[2] + wsum[3];
  float sc = rsqrtf(tot * (1.f / 1024.f) + 1e-6f);
  float4 wv = ((const float4*)w)[t];
  float4 o;
  o.x = v0 * sc * wv.x; o.y = v1 * sc * wv.y;
  o.z = v2 * sc * wv.z; o.w = v3 * sc * wv.w;
  ((float4*)(out + (size_t)row * 1024))[t] = o;
}

// ---------------- generic MFMA GEMM 128x128 (EP1 gate-fused, EP5 plain) ----------------

struct EpA {
  bf16* outb;
  const float* bias;
  const bf16* encb;
  const float* p;
  const int* bucket;
  const float* smoothed;
};

template <int EP>
__global__ __launch_bounds__(256) void gemm_bt(const bf16* __restrict__ A,
                                               const bf16* __restrict__ W,
                                               int N, int K, EpA ep) {
  __shared__ __align__(16) bf16 As[128 * 64];
  __shared__ __align__(16) bf16 Bs[128 * 64];
  const int t = threadIdx.x;
  const int lane = t & 63;
  const int wv = t >> 6;
  const int wm = wv >> 1, wn = wv & 1;
  const int quad = lane >> 4, l16 = lane & 15;
  const int bm = blockIdx.x << 7, bn = blockIdx.y << 7;

  f32x4 acc[4][4] = {};

  for (int k0 = 0; k0 < K; k0 += 64) {
    __syncthreads();
#pragma unroll
    for (int i = 0; i < 4; ++i) {
      int slot = i * 256 + t;
      int m = slot >> 3;
      int lk8 = (slot & 7) ^ (m & 7);
      gl_lds16(A + (size_t)(bm + m) * K + k0 + lk8 * 8, As + slot * 8);
      gl_lds16(W + (size_t)(bn + m) * K + k0 + lk8 * 8, Bs + slot * 8);
    }
    __syncthreads();
#pragma unroll
    for (int ks = 0; ks < 2; ++ks) {
      short8 af[4], bfr[4];
#pragma unroll
      for (int i = 0; i < 4; ++i) {
        int m = wm * 64 + i * 16 + l16;
        int pa = (ks * 4 + quad) ^ (m & 7);
        af[i] = *(const short8*)(As + m * 64 + pa * 8);
        int n = wn * 64 + i * 16 + l16;
        int pb = (ks * 4 + quad) ^ (n & 7);
        bfr[i] = *(const short8*)(Bs + n * 64 + pb * 8);
      }
#pragma unroll
      for (int i = 0; i < 4; ++i)
#pragma unroll
        for (int j = 0; j < 4; ++j)
          acc[i][j] = __builtin_amdgcn_mfma_f32_16x16x32_bf16(af[i], bfr[j], acc[i][j], 0, 0, 0);
    }
  }

#pragma unroll
  for (int i = 0; i < 4; ++i) {
#pragma unroll
    for (int j = 0; j < 4; ++j) {
#pragma unroll
      for (int r = 0; r < 4; ++r) {
        int m = bm + wm * 64 + i * 16 + quad * 4 + r;
        int n = bn + wn * 64 + j * 16 + l16;
        size_t idx = (size_t)m * N + n;
        float v = acc[i][j][r];
        if (EP == 1) {         // gate + plugback (N == DMODEL)
          float g = sigm(v + ep.bias[n]);
          float pm = ep.p[m];
          int bb = m >> 11;
          float sm = ep.smoothed[((size_t)(bb * NM + ep.bucket[m])) * DMODEL + n];
          float e = __bfloat162float(ep.encb[idx]);
          ep.outb[idx] = __float2bfloat16((1.f - pm) * g * e + sm);
        } else {               // EP == 5: plain bf16 out
          ep.outb[idx] = __float2bfloat16(v);
        }
      }
    }
  }
}

// ---------------- dual GEMM: r & i heads share A, fused a_t/s_t epilogue ----------------
// A = xconv bf16 [BLR,256]; Wr,Wi [256,256]. Writes packed uint{d=1-a bf16, s bf16}.

__global__ __launch_bounds__(256) void gemm_ri(const bf16* __restrict__ A,
                                               const bf16* __restrict__ Wr,
                                               const bf16* __restrict__ Wi,
                                               const float* __restrict__ rbias,
                                               const float* __restrict__ ibias,
                                               const float* __restrict__ e8,
                                               unsigned int* __restrict__ ds_out) {
  __shared__ __align__(16) bf16 As[128 * 64];
  __shared__ __align__(16) bf16 Br[128 * 64];
  __shared__ __align__(16) bf16 Bi[128 * 64];
  const int t = threadIdx.x;
  const int lane = t & 63;
  const int wv = t >> 6;
  const int wm = wv >> 1, wn = wv & 1;
  const int quad = lane >> 4, l16 = lane & 15;
  const int bm = blockIdx.x << 7, bn = blockIdx.y << 7;

  f32x4 ar[4][4] = {};
  f32x4 ai[4][4] = {};

  for (int k0 = 0; k0 < DO; k0 += 64) {
    __syncthreads();
#pragma unroll
    for (int i = 0; i < 4; ++i) {
      int slot = i * 256 + t;
      int m = slot >> 3;
      int lk8 = (slot & 7) ^ (m & 7);
      gl_lds16(A + (size_t)(bm + m) * DO + k0 + lk8 * 8, As + slot * 8);
      gl_lds16(Wr + (size_t)(bn + m) * DO + k0 + lk8 * 8, Br + slot * 8);
      gl_lds16(Wi + (size_t)(bn + m) * DO + k0 + lk8 * 8, Bi + slot * 8);
    }
    __syncthreads();
#pragma unroll
    for (int ks = 0; ks < 2; ++ks) {
      short8 af[4], br[4], bi[4];
#pragma unroll
      for (int i = 0; i < 4; ++i) {
        int m = wm * 64 + i * 16 + l16;
        int pa = (ks * 4 + quad) ^ (m & 7);
        af[i] = *(const short8*)(As + m * 64 + pa * 8);
        int n = wn * 64 + i * 16 + l16;
        int pb = (ks * 4 + quad) ^ (n & 7);
        br[i] = *(const short8*)(Br + n * 64 + pb * 8);
        bi[i] = *(const short8*)(Bi + n * 64 + pb * 8);
      }
#pragma unroll
      for (int i = 0; i < 4; ++i)
#pragma unroll
        for (int j = 0; j < 4; ++j) {
          ar[i][j] = __builtin_amdgcn_mfma_f32_16x16x32_bf16(af[i], br[j], ar[i][j], 0, 0, 0);
          ai[i][j] = __builtin_amdgcn_mfma_f32_16x16x32_bf16(af[i], bi[j], ai[i][j], 0, 0, 0);
        }
    }
  }

#pragma unroll
  for (int i = 0; i < 4; ++i) {
#pragma unroll
    for (int j = 0; j < 4; ++j) {
#pragma unroll
      for (int r = 0; r < 4; ++r) {
        int m = bm + wm * 64 + i * 16 + quad * 4 + r;
        int n = bn + wn * 64 + j * 16 + l16;
        size_t idx = (size_t)m * DO + n;
        float rv = sigm(ar[i][j][r] + rbias[n]);
        float a = exp2f(rv * e8[n]);
        float d = 1.f - a;                               // ~5e-3, bf16-safe
        float iv = sigm(ai[i][j][r] + ibias[n]);
        float xc = __bfloat162float(A[idx]);             // xconv[m][n] == A[m][n]
        float s = sqrtf(fmaxf(1.f - a * a, 0.f)) * iv * xc;
        ds_out[idx] = (unsigned int)bf16bits(d) | ((unsigned int)bf16bits(s) << 16);
      }
    }
  }
}

// ---------------- out-proj GEMM tile 64x256 + fused RMSNorm(256) ----------------

__global__ __launch_bounds__(256) void gemm_on(const bf16* __restrict__ A,   // hs [BLR,256]
                                               const bf16* __restrict__ W,   // ow [256,256]
                                               const float* __restrict__ rnw,
                                               bf16* __restrict__ xb) {
  __shared__ __align__(16) bf16 As[64 * 64];
  __shared__ __align__(16) bf16 Bs[256 * 64];
  __shared__ float red[4][64];
  const int t = threadIdx.x;
  const int lane = t & 63;
  const int wn = t >> 6;           // wave = column slice of 64
  const int quad = lane >> 4, l16 = lane & 15;
  const int bm = blockIdx.x << 6;

  f32x4 acc[4][4] = {};

  for (int k0 = 0; k0 < DO; k0 += 64) {
    __syncthreads();
#pragma unroll
    for (int i = 0; i < 2; ++i) {
      int slot = i * 256 + t;
      int m = slot >> 3;
      int lk8 = (slot & 7) ^ (m & 7);
      gl_lds16(A + (size_t)(bm + m) * DO + k0 + lk8 * 8, As + slot * 8);
    }
#pragma unroll
    for (int i = 0; i < 8; ++i) {
      int slot = i * 256 + t;
      int n = slot >> 3;
      int lk8 = (slot & 7) ^ (n & 7);
      gl_lds16(W + (size_t)n * DO + k0 + lk8 * 8, Bs + slot * 8);
    }
    __syncthreads();
#pragma unroll
    for (int ks = 0; ks < 2; ++ks) {
      short8 af[4], bfr[4];
#pragma unroll
      for (int i = 0; i < 4; ++i) {
        int m = i * 16 + l16;
        int pa = (ks * 4 + quad) ^ (m & 7);
        af[i] = *(const short8*)(As + m * 64 + pa * 8);
        int n = wn * 64 + i * 16 + l16;
        int pb = (ks * 4 + quad) ^ (n & 7);
        bfr[i] = *(const short8*)(Bs + n * 64 + pb * 8);
      }
#pragma unroll
      for (int i = 0; i < 4; ++i)
#pragma unroll
        for (int j = 0; j < 4; ++j)
          acc[i][j] = __builtin_amdgcn_mfma_f32_16x16x32_bf16(af[i], bfr[j], acc[i][j], 0, 0, 0);
    }
  }

  float part[4][4];
#pragma unroll
  for (int i = 0; i < 4; ++i)
#pragma unroll
    for (int r = 0; r < 4; ++r) {
      float s = 0.f;
#pragma unroll
      for (int j = 0; j < 4; ++j) s += acc[i][j][r] * acc[i][j][r];
      part[i][r] = s;
    }
#pragma unroll
  for (int mask = 1; mask <= 8; mask <<= 1)
#pragma unroll
    for (int i = 0; i < 4; ++i)
#pragma unroll
      for (int r = 0; r < 4; ++r) part[i][r] += __shfl_xor(part[i][r], mask, 64);
  if (l16 == 0) {
#pragma unroll
    for (int i = 0; i < 4; ++i)
#pragma unroll
      for (int r = 0; r < 4; ++r) red[wn][i * 16 + quad * 4 + r] = part[i][r];
  }
  __syncthreads();
#pragma unroll
  for (int i = 0; i < 4; ++i) {
#pragma unroll
    for (int r = 0; r < 4; ++r) {
      int ml = i * 16 + quad * 4 + r;
      float tot = red[0][ml] + red[1][ml] + red[2][ml] + red[3][ml];
      float sc = rsqrtf(tot * (1.f / 256.f) + 1e-6f);
#pragma unroll
      for (int j = 0; j < 4; ++j) {
        int n = wn * 64 + j * 16 + l16;
        xb[(size_t)(bm + ml) * DO + n] = __float2bfloat16(acc[i][j][r] * sc * rnw[n]);
      }
    }
  }
}

// ---------------- launch ----------------

extern "C" void kernel_launch(void* const* d_in, const int* in_sizes, int n_in,
                              void* d_out, int out_size, void* d_ws, size_t ws_size,
                              hipStream_t stream) {
  const float* concept_out = (const float*)d_in[0];
  const float* encoder_out = (const float*)d_in[1];
  const float* bprobs      = (const float*)d_in[2];
  const int*   bidx        = (const int*)d_in[3];
  const float* gate_w      = (const float*)d_in[4];
  const float* gate_b      = (const float*)d_in[5];
  const float* down_w      = (const float*)d_in[6];
  const float* up_w        = (const float*)d_in[7];
  const float* norm_out_w  = (const float*)d_in[8];
  const float* rc_w        = (const float*)d_in[9];
  const float* rc_b        = (const float*)d_in[10];
  const float* wr_w        = (const float*)d_in[11];
  const float* wr_b        = (const float*)d_in[12];
  const float* wi_w        = (const float*)d_in[13];
  const float* wi_b        = (const float*)d_in[14];
  const float* log_a       = (const float*)d_in[15];
  const float* ow_w        = (const float*)d_in[16];
  const float* rn_w        = (const float*)d_in[17];
  float* out = (float*)d_out;
  (void)in_sizes; (void)n_in; (void)out_size; (void)ws_size;

  char* base = (char*)d_ws;
  size_t off = 0;
  auto alloc = [&](size_t bytes) -> char* {
    char* p = base + off;
    off += (bytes + 255) & ~(size_t)255;
    return p;
  };
  float* smoothed = (float*)alloc((size_t)NB * NM * DMODEL * 4);   // 8 MB
  int*   bucket   = (int*)alloc((size_t)BLR * 4);
  bf16*  gate_wb  = (bf16*)alloc((size_t)DMODEL * DMODEL * 2);
  bf16*  down_wb  = (bf16*)alloc((size_t)DO * DMODEL * 2);
  bf16*  up_wb    = (bf16*)alloc((size_t)DMODEL * DO * 2);
  bf16*  wrb      = (bf16*)alloc((size_t)3 * DO * DO * 2);
  bf16*  wib      = (bf16*)alloc((size_t)3 * DO * DO * 2);
  bf16*  owb      = (bf16*)alloc((size_t)3 * DO * DO * 2);
  float* e8       = (float*)alloc(3 * DO * 4);
  float2* ASsum   = (float2*)alloc((size_t)NB * NCH * DO * 8);     // 512 KB chunk summaries
  bf16*  xb       = (bf16*)alloc((size_t)BLR * DO * 2);            // 8 MB layer io

  // reused overlay region — offsets computed from actual buffer sizes
  const size_t SZ_ENC   = (size_t)BLR * DMODEL * 2;   // 32 MB
  const size_t SZ_XCONV = (size_t)BLR * DO * 2;       //  8 MB
  const size_t SZ_DS    = (size_t)BLR * DO * 4;       // 16 MB (packed uint32!)
  char* RA = alloc(2 * SZ_ENC);                       // 64 MB
  // head overlays
  bf16*  encb = (bf16*)RA;
  bf16*  h0b  = (bf16*)(RA + SZ_ENC);
  // layer overlays (xconvb | dsbuf | hsb disjoint: 8 + 16 + 8 = 32 MB)
  bf16*         xconvb = (bf16*)RA;
  unsigned int* dsbuf  = (unsigned int*)(RA + SZ_XCONV);
  bf16*         hsb    = (bf16*)(RA + SZ_XCONV + SZ_DS);
  // tail overlay
  bf16*  tmp2b  = (bf16*)RA;

  cvt4_kernel<<<(BLR * DMODEL / 4 + 255) / 256, 256, 0, stream>>>(
      (const float4*)encoder_out, (ushort4*)encb, BLR * DMODEL / 4);
  prep_kernel<<<(2163456 + 255) / 256, 256, 0, stream>>>(
      gate_w, down_w, up_w, wr_w, wi_w, ow_w, log_a,
      gate_wb, down_wb, up_wb, wrb, wib, owb, e8);
  ema_kernel<<<NB * 4, 256, 0, stream>>>(concept_out, bprobs, bidx, smoothed);
  bucket_kernel<<<BLR / 256, 256, 0, stream>>>(bidx, bucket);

  EpA ep;
  // G1: gate GEMM + fused gated residual + plugback -> h0 (bf16)
  ep = EpA{};
  ep.outb = h0b; ep.bias = gate_b; ep.encb = encb; ep.p = bprobs;
  ep.bucket = bucket; ep.smoothed = smoothed;
  gemm_bt<1><<<dim3(BLR / 128, DMODEL / 128), 256, 0, stream>>>(encb, gate_wb, DMODEL, DMODEL, ep);
  // G2: down projection -> xb (bf16)
  ep = EpA{}; ep.outb = xb;
  gemm_bt<5><<<dim3(BLR / 128, DO / 128), 256, 0, stream>>>(h0b, down_wb, DO, DMODEL, ep);

  for (int k = 0; k < 3; ++k) {
    conv_kernel<<<BLR, 256, 0, stream>>>(xb, rc_w + k * DO * 4, rc_b + k * DO, xconvb);
    gemm_ri<<<dim3(BLR / 128, DO / 128), 256, 0, stream>>>(
        xconvb, wrb + k * DO * DO, wib + k * DO * DO,
        wr_b + k * DO, wi_b + k * DO, e8 + k * DO, dsbuf);
    scan_p1<<<NB * NCH, 256, 0, stream>>>(dsbuf, ASsum);
    scan_p2<<<NB * NCH, 256, 0, stream>>>(dsbuf, ASsum, hsb);
    gemm_on<<<BLR / 64, 256, 0, stream>>>(hsb, owb + k * DO * DO, rn_w + k * DO, xb);
  }

  // up projection -> tmp2 (bf16), final rmsnorm -> out (f32)
  ep = EpA{}; ep.outb = tmp2b;
  gemm_bt<5><<<dim3(BLR / 128, DMODEL / 128), 256, 0, stream>>>(xb, up_wb, DMODEL, DO, ep);
  rmsnorm1024_kernel<<<BLR, 256, 0, stream>>>(tmp2b, norm_out_w, out);
}